// Round 1
// baseline (4989.034 us; speedup 1.0000x reference)
//
#include <hip/hip_runtime.h>
#include <stdint.h>

typedef float f32x4 __attribute__((ext_vector_type(4)));

#define NB 2048
#define NS 128
#define NI 8
#define NH 256
#define NG 1024   // 4*H
#define NK 50

#define A_SC 16.0f
#define W_SC 32.0f
#define INV_SC (1.0f/(A_SC*W_SC))

// IDM constants
#define DT_    0.1f
#define V_DES_ 12.64798288f
#define T_HW_  0.50284384f
#define A_MAX_ 0.10033688f
#define B_SAFE_ 4.98937183f
#define S0_    0.13082412f

// swizzled LDS address for h buffers: 16 rows x 256 bytes, XOR slot swizzle
// (spreads the stride-256 ds_read_b64 column access across banks)
#define HADDR(row, boff) (((row) << 8) + ((((((boff) >> 3) ^ ((row) << 1)) & 31)) << 3) + ((boff) & 7))

__device__ __forceinline__ uint8_t f2fp8(float v) {
    int r = __builtin_amdgcn_cvt_pk_fp8_f32(v, v, 0, false);
    return (uint8_t)(r & 0xff);
}

__device__ __forceinline__ float sigm(float x) { return 1.0f / (1.0f + __expf(-x)); }
__device__ __forceinline__ float tanh_f(float x) {
    x = fminf(fmaxf(x, -15.0f), 15.0f);
    float e = __expf(2.0f * x);
    return (e - 1.0f) / (e + 1.0f);
}

// ---------------- pre-pass kernels ----------------

// Pack W [Nsrc][Ksrc] (f32 row-major) into MFMA B-frag order:
// out[((tile*KB + kb)*64 + lane)*8 + j] = fp8(W[tile*16 + (lane&15)][kb*32 + (lane>>4)*8 + j] * W_SC)
__global__ void k_pack(const float* __restrict__ W, uint8_t* __restrict__ out,
                       int tiles, int KB, int Nsrc, int Ksrc) {
    int gid = blockIdx.x * 256 + threadIdx.x;
    int total = tiles * KB * 64;
    if (gid >= total) return;
    int lane = gid & 63;
    int kb   = (gid >> 6) % KB;
    int tile = gid / (64 * KB);
    int n = tile * 16 + (lane & 15);
    int kbase = kb * 32 + (lane >> 4) * 8;
    uint64_t wbits = 0;
    #pragma unroll
    for (int j = 0; j < 8; ++j) {
        int k = kbase + j;
        float v = (n < Nsrc && k < Ksrc) ? W[(size_t)n * Ksrc + k] * W_SC : 0.0f;
        wbits |= ((uint64_t)f2fp8(v)) << (8 * j);
    }
    *(uint64_t*)(out + (size_t)gid * 8) = wbits;
}

__global__ void k_bias(const float* __restrict__ bih0, const float* __restrict__ bhh0,
                       const float* __restrict__ bih1, const float* __restrict__ bhh1,
                       float* __restrict__ b0, float* __restrict__ b1) {
    int i = blockIdx.x * 256 + threadIdx.x;
    if (i < NG) b0[i] = bih0[i] + bhh0[i];
    else if (i < 2 * NG) b1[i - NG] = bih1[i - NG] + bhh1[i - NG];
}

__global__ void k_x8(const float* __restrict__ x, uint8_t* __restrict__ x8) {
    int i = blockIdx.x * 256 + threadIdx.x;
    if (i < NB * NS * NI) x8[i] = f2fp8(x[i] * A_SC);
}

// ---------------- main persistent LSTM kernel ----------------
// 256 WGs x 512 threads. WG owns 8 batch rows for all 128 steps (no inter-WG comm).
// Wave w owns hidden units [32w, 32w+32) of both layers: tiles {16g + 2w + j}.

__global__ __launch_bounds__(512, 2)
void k_lstm(const uint8_t* __restrict__ x8,
            const uint8_t* __restrict__ Wih0P, const uint8_t* __restrict__ Whh0P,
            const uint8_t* __restrict__ Wih1P, const uint8_t* __restrict__ Whh1P,
            const uint8_t* __restrict__ WfcP,
            const float* __restrict__ bias0, const float* __restrict__ bias1,
            const float* __restrict__ bfc,
            float* __restrict__ out) {
    __shared__ uint8_t h0s[2][4096];   // [parity][HADDR(row<16, byte<256)]
    __shared__ uint8_t h1s[2][4096];

    const int tid  = threadIdx.x;
    const int w    = tid >> 6;
    const int lane = tid & 63;
    const int lrow = lane & 15;
    const int kgrp = lane >> 4;
    const int rowb = blockIdx.x * 8;

    // zero-init h buffers (rows 8..15 stay zero forever)
    {
        int* a = (int*)h0s; int* b = (int*)h1s;
        #pragma unroll
        for (int i = 0; i < 4; ++i) { a[tid + i * 512] = 0; b[tid + i * 512] = 0; }
    }

    // per-lane biases for this wave's 8 tiles
    float bs0[4][2], bs1[4][2];
    #pragma unroll
    for (int g = 0; g < 4; ++g)
        #pragma unroll
        for (int j = 0; j < 2; ++j) {
            int n = g * 256 + w * 32 + j * 16 + lrow;
            bs0[g][j] = bias0[n];
            bs1[g][j] = bias1[n];
        }

    float c0v[2][4], c1v[2][4];
    #pragma unroll
    for (int j = 0; j < 2; ++j)
        #pragma unroll
        for (int r = 0; r < 4; ++r) { c0v[j][r] = 0.0f; c1v[j][r] = 0.0f; }

    const int arow = rowb + (lrow & 7);     // duplicate rows 8-15 -> garbage C rows, ignored
    __syncthreads();

    for (int t = 0; t < NS; ++t) {
        const int p = t & 1;

        // ===== layer 0: g0 = x_t @ Wih0^T + h0 @ Whh0^T =====
        f32x4 acc[4][2];
        #pragma unroll
        for (int g = 0; g < 4; ++g)
            #pragma unroll
            for (int j = 0; j < 2; ++j) acc[g][j] = (f32x4){0.f, 0.f, 0.f, 0.f};

        {   // K-block 0: x (K=8, zero padded to 32)
            long a0 = 0;
            if (kgrp == 0) a0 = *(const long*)(x8 + (size_t)arow * (NS * NI) + t * NI);
            #pragma unroll
            for (int g = 0; g < 4; ++g)
                #pragma unroll
                for (int j = 0; j < 2; ++j) {
                    int tile = g * 16 + w * 2 + j;
                    long bf = *(const long*)(Wih0P + ((size_t)tile * 64 + lane) * 8);
                    acc[g][j] = __builtin_amdgcn_mfma_f32_16x16x32_fp8_fp8(a0, bf, acc[g][j], 0, 0, 0);
                }
        }
        #pragma unroll
        for (int kb = 0; kb < 8; ++kb) {
            long af = *(const long*)(&h0s[p][HADDR(lrow, kb * 32 + kgrp * 8)]);
            #pragma unroll
            for (int g = 0; g < 4; ++g)
                #pragma unroll
                for (int j = 0; j < 2; ++j) {
                    int tile = g * 16 + w * 2 + j;
                    long bf = *(const long*)(Whh0P + (((size_t)tile * 8 + kb) * 64 + lane) * 8);
                    acc[g][j] = __builtin_amdgcn_mfma_f32_16x16x32_fp8_fp8(af, bf, acc[g][j], 0, 0, 0);
                }
        }
        // gates -> c0, h0_new -> h0s[1-p]
        #pragma unroll
        for (int j = 0; j < 2; ++j)
            #pragma unroll
            for (int r = 0; r < 4; ++r) {
                float iv = acc[0][j][r] * INV_SC + bs0[0][j];
                float fv = acc[1][j][r] * INV_SC + bs0[1][j];
                float gv = acc[2][j][r] * INV_SC + bs0[2][j];
                float ov = acc[3][j][r] * INV_SC + bs0[3][j];
                float c = sigm(fv) * c0v[j][r] + sigm(iv) * tanh_f(gv);
                c0v[j][r] = c;
                float h = sigm(ov) * tanh_f(c);
                if (lane < 32) {
                    int row = kgrp * 4 + r;
                    int u = w * 32 + j * 16 + lrow;
                    h0s[1 - p][HADDR(row, u)] = f2fp8(h * A_SC);
                }
            }
        __syncthreads();

        // ===== layer 1: g1 = h0_new @ Wih1^T + h1 @ Whh1^T =====
        #pragma unroll
        for (int g = 0; g < 4; ++g)
            #pragma unroll
            for (int j = 0; j < 2; ++j) acc[g][j] = (f32x4){0.f, 0.f, 0.f, 0.f};

        #pragma unroll
        for (int kb = 0; kb < 8; ++kb) {
            long af = *(const long*)(&h0s[1 - p][HADDR(lrow, kb * 32 + kgrp * 8)]);
            #pragma unroll
            for (int g = 0; g < 4; ++g)
                #pragma unroll
                for (int j = 0; j < 2; ++j) {
                    int tile = g * 16 + w * 2 + j;
                    long bf = *(const long*)(Wih1P + (((size_t)tile * 8 + kb) * 64 + lane) * 8);
                    acc[g][j] = __builtin_amdgcn_mfma_f32_16x16x32_fp8_fp8(af, bf, acc[g][j], 0, 0, 0);
                }
        }
        #pragma unroll
        for (int kb = 0; kb < 8; ++kb) {
            long af = *(const long*)(&h1s[p][HADDR(lrow, kb * 32 + kgrp * 8)]);
            #pragma unroll
            for (int g = 0; g < 4; ++g)
                #pragma unroll
                for (int j = 0; j < 2; ++j) {
                    int tile = g * 16 + w * 2 + j;
                    long bf = *(const long*)(Whh1P + (((size_t)tile * 8 + kb) * 64 + lane) * 8);
                    acc[g][j] = __builtin_amdgcn_mfma_f32_16x16x32_fp8_fp8(af, bf, acc[g][j], 0, 0, 0);
                }
        }
        #pragma unroll
        for (int j = 0; j < 2; ++j)
            #pragma unroll
            for (int r = 0; r < 4; ++r) {
                float iv = acc[0][j][r] * INV_SC + bs1[0][j];
                float fv = acc[1][j][r] * INV_SC + bs1[1][j];
                float gv = acc[2][j][r] * INV_SC + bs1[2][j];
                float ov = acc[3][j][r] * INV_SC + bs1[3][j];
                float c = sigm(fv) * c1v[j][r] + sigm(iv) * tanh_f(gv);
                c1v[j][r] = c;
                float h = sigm(ov) * tanh_f(c);
                if (lane < 32) {
                    int row = kgrp * 4 + r;
                    int u = w * 32 + j * 16 + lrow;
                    h1s[1 - p][HADDR(row, u)] = f2fp8(h * A_SC);
                }
            }
        __syncthreads();
    }

    // ===== FC head: y = h1_final @ Wfc^T + bfc  (final parity buffer = h1s[0]) =====
    if (w < 4) {
        f32x4 accf = (f32x4){0.f, 0.f, 0.f, 0.f};
        #pragma unroll
        for (int kb = 0; kb < 8; ++kb) {
            long af = *(const long*)(&h1s[0][HADDR(lrow, kb * 32 + kgrp * 8)]);
            long bf = *(const long*)(WfcP + (((size_t)w * 8 + kb) * 64 + lane) * 8);
            accf = __builtin_amdgcn_mfma_f32_16x16x32_fp8_fp8(af, bf, accf, 0, 0, 0);
        }
        int col = w * 16 + lrow;
        if (lane < 32 && col < NK) {
            float bb = bfc[col];
            #pragma unroll
            for (int r = 0; r < 4; ++r) {
                int row = kgrp * 4 + r;
                out[(size_t)(rowb + row) * NK + col] = accf[r] * INV_SC + bb;
            }
        }
    }
}

// ---------------- IDM rollout (exact fp32) ----------------
__global__ void k_idm(const float* __restrict__ x, const float* __restrict__ s0,
                      const float* __restrict__ vl, float* __restrict__ out) {
    int b = blockIdx.x * 256 + threadIdx.x;
    if (b >= NB) return;
    float v = x[(size_t)b * NS * NI + (NS - 1) * NI + 0];
    float s = s0[b];
    float vlead = vl[b];
    const float den = 2.0f * sqrtf(A_MAX_ * B_SAFE_) + 1e-6f;
    float* o = out + (size_t)NB * NK + (size_t)b * NK;
    #pragma unroll 1
    for (int k = 0; k < NK; ++k) {
        float dv = vlead - v;
        float sc = fmaxf(s, 1e-6f);
        float ss = fmaxf(S0_ + v * T_HW_ + v * dv / den, 0.0f);
        float a = A_MAX_ * (1.0f - v / V_DES_ - (ss / sc) * (ss / sc));
        v = fmaxf(v + DT_ * a, 0.0f);
        s = fmaxf(s + dv * DT_, 1e-6f);
        o[k] = v;
    }
}

// ---------------- launch ----------------
extern "C" void kernel_launch(void* const* d_in, const int* in_sizes, int n_in,
                              void* d_out, int out_size, void* d_ws, size_t ws_size,
                              hipStream_t stream) {
    const float* x    = (const float*)d_in[0];
    const float* s0   = (const float*)d_in[1];
    const float* vl   = (const float*)d_in[2];
    const float* Wih0 = (const float*)d_in[3];
    const float* Whh0 = (const float*)d_in[4];
    const float* bih0 = (const float*)d_in[5];
    const float* bhh0 = (const float*)d_in[6];
    const float* Wih1 = (const float*)d_in[7];
    const float* Whh1 = (const float*)d_in[8];
    const float* bih1 = (const float*)d_in[9];
    const float* bhh1 = (const float*)d_in[10];
    const float* Wfc  = (const float*)d_in[11];
    const float* bfc  = (const float*)d_in[12];
    float* out = (float*)d_out;

    uint8_t* ws = (uint8_t*)d_ws;
    size_t off = 0;
    auto alloc = [&](size_t n) { uint8_t* p = ws + off; off += (n + 255) & ~(size_t)255; return p; };
    uint8_t* Wih0P = alloc(64 * 1 * 64 * 8);
    uint8_t* Whh0P = alloc(64 * 8 * 64 * 8);
    uint8_t* Wih1P = alloc(64 * 8 * 64 * 8);
    uint8_t* Whh1P = alloc(64 * 8 * 64 * 8);
    uint8_t* WfcP  = alloc(4 * 8 * 64 * 8);
    float* b0 = (float*)alloc(NG * 4);
    float* b1 = (float*)alloc(NG * 4);
    uint8_t* x8 = alloc((size_t)NB * NS * NI);

    k_pack<<<(64 * 1 * 64 + 255) / 256, 256, 0, stream>>>(Wih0, Wih0P, 64, 1, NG, NI);
    k_pack<<<(64 * 8 * 64 + 255) / 256, 256, 0, stream>>>(Whh0, Whh0P, 64, 8, NG, NH);
    k_pack<<<(64 * 8 * 64 + 255) / 256, 256, 0, stream>>>(Wih1, Wih1P, 64, 8, NG, NH);
    k_pack<<<(64 * 8 * 64 + 255) / 256, 256, 0, stream>>>(Whh1, Whh1P, 64, 8, NG, NH);
    k_pack<<<(4 * 8 * 64 + 255) / 256, 256, 0, stream>>>(Wfc, WfcP, 4, 8, NK, NH);
    k_bias<<<(2 * NG + 255) / 256, 256, 0, stream>>>(bih0, bhh0, bih1, bhh1, b0, b1);
    k_x8<<<(NB * NS * NI + 255) / 256, 256, 0, stream>>>(x, x8);
    k_lstm<<<256, 512, 0, stream>>>(x8, Wih0P, Whh0P, Wih1P, Whh1P, WfcP, b0, b1, bfc, out);
    k_idm<<<(NB + 255) / 256, 256, 0, stream>>>(x, s0, vl, out);
}

// Round 2
// 2589.646 us; speedup vs baseline: 1.9265x; 1.9265x over previous
//
#include <hip/hip_runtime.h>
#include <stdint.h>

typedef float f32x4 __attribute__((ext_vector_type(4)));
typedef unsigned int uint;

#define NB 2048
#define NS 128
#define NI 8
#define NH 256
#define NG 1024   // 4*H
#define NK 50

#define A_SC 16.0f
#define W_SC 32.0f
#define INV_SC (1.0f/(A_SC*W_SC))

// IDM constants
#define DT_    0.1f
#define V_DES_ 12.64798288f
#define T_HW_  0.50284384f
#define A_MAX_ 0.10033688f
#define B_SAFE_ 4.98937183f
#define S0_    0.13082412f

// swizzled LDS address for h stage buffers: [64 rows][256 bytes], XOR granule swizzle
#define HADDR(row, boff) (((row) << 8) + (((((boff) >> 3) ^ (((row) & 15) << 1)) & 31) << 3) + ((boff) & 7))
// gate buffer: [64 rows][128 cols] f32, XOR column swizzle (conflict-free C-writes & gate reads)
#define GIDX(row, col) (((row) << 7) + ((col) ^ (((row) & 12) << 2)))

__device__ __forceinline__ uint8_t f2fp8(float v) {
    int r = __builtin_amdgcn_cvt_pk_fp8_f32(v, v, 0, false);
    return (uint8_t)(r & 0xff);
}
__device__ __forceinline__ float sigm(float x) { return 1.0f / (1.0f + __expf(-x)); }
__device__ __forceinline__ float tanh_f(float x) {
    x = fminf(fmaxf(x, -15.0f), 15.0f);
    float e = __expf(2.0f * x);
    return (e - 1.0f) / (e + 1.0f);
}

// ---------------- pre-pass kernels ----------------
__global__ void k_pack(const float* __restrict__ W, uint8_t* __restrict__ out,
                       int tiles, int KB, int Nsrc, int Ksrc) {
    int gid = blockIdx.x * 256 + threadIdx.x;
    int total = tiles * KB * 64;
    if (gid >= total) return;
    int lane = gid & 63;
    int kb   = (gid >> 6) % KB;
    int tile = gid / (64 * KB);
    int n = tile * 16 + (lane & 15);
    int kbase = kb * 32 + (lane >> 4) * 8;
    uint64_t wbits = 0;
    #pragma unroll
    for (int j = 0; j < 8; ++j) {
        int k = kbase + j;
        float v = (n < Nsrc && k < Ksrc) ? W[(size_t)n * Ksrc + k] * W_SC : 0.0f;
        wbits |= ((uint64_t)f2fp8(v)) << (8 * j);
    }
    *(uint64_t*)(out + (size_t)gid * 8) = wbits;
}

__global__ void k_bias(const float* __restrict__ bih0, const float* __restrict__ bhh0,
                       const float* __restrict__ bih1, const float* __restrict__ bhh1,
                       float* __restrict__ b0, float* __restrict__ b1) {
    int i = blockIdx.x * 256 + threadIdx.x;
    if (i < NG) b0[i] = bih0[i] + bhh0[i];
    else if (i < 2 * NG) b1[i - NG] = bih1[i - NG] + bhh1[i - NG];
}

__global__ void k_x8(const float* __restrict__ x, uint8_t* __restrict__ x8) {
    int i = blockIdx.x * 256 + threadIdx.x;
    if (i < NB * NS * NI) x8[i] = f2fp8(x[i] * A_SC);
}

// ---------------- fused weight-stationary LSTM ----------------
// 256 WGs = 32 batch-groups x 8 gate-slices. Weights live in VGPRs for the
// whole kernel; h slices are exchanged via global memory + per-group
// device-scope atomic barrier once per phase (129 phases, layers pipelined).
__global__ __launch_bounds__(512, 2)
void k_lstm2(const uint8_t* __restrict__ x8,
             const uint8_t* __restrict__ Wih0P, const uint8_t* __restrict__ Whh0P,
             const uint8_t* __restrict__ Wih1P, const uint8_t* __restrict__ Whh1P,
             const uint8_t* __restrict__ WfcP,
             const float* __restrict__ bias0, const float* __restrict__ bias1,
             const float* __restrict__ bfc,
             uint8_t* __restrict__ h0g, uint8_t* __restrict__ h1g,
             uint* __restrict__ ctrs, float* __restrict__ out) {
    __shared__ uint8_t h0st[16384];   // h0[prev] fp8, HADDR layout
    __shared__ uint8_t h1st[16384];   // h1[prev-1] fp8
    __shared__ float gbuf[8192];      // gate staging, GIDX layout

    const int tid  = threadIdx.x;
    const int w    = tid >> 6, lane = tid & 63;
    const int lrow = lane & 15, kgrp = lane >> 4;
    const int blk  = blockIdx.x;
    const int grp  = blk & 31, slc = blk >> 5;
    const int rowbase = grp * 64;
    const int ctp = w & 3, rtp = w >> 2;   // wave owns col-tiles {2ctp,2ctp+1}, row-tiles {2rtp,2rtp+1}

    // ---- persistent weight fragments in VGPRs (read HBM exactly once) ----
    long wI0[2], wH0[2][8], wI1[2][8], wH1[2][8];
    #pragma unroll
    for (int cc = 0; cc < 2; ++cc) {
        int ct = ctp * 2 + cc;
        int T  = (ct >> 1) * 16 + slc * 2 + (ct & 1);   // global 16-out tile index
        wI0[cc] = *(const long*)(Wih0P + ((size_t)T * 64 + lane) * 8);
        #pragma unroll
        for (int kb = 0; kb < 8; ++kb) {
            wH0[cc][kb] = *(const long*)(Whh0P + (((size_t)T * 8 + kb) * 64 + lane) * 8);
            wI1[cc][kb] = *(const long*)(Wih1P + (((size_t)T * 8 + kb) * 64 + lane) * 8);
            wH1[cc][kb] = *(const long*)(Whh1P + (((size_t)T * 8 + kb) * 64 + lane) * 8);
        }
    }

    // nonlinearity ownership: thread -> unit uu (of 32), rows rb..rb+3
    const int uu = tid & 31;
    const int rb = (tid >> 5) * 4;
    float bs0[4], bs1[4];
    #pragma unroll
    for (int g = 0; g < 4; ++g) {
        int n = g * 256 + slc * 32 + uu;
        bs0[g] = bias0[n]; bs1[g] = bias1[n];
    }
    float c0v[4] = {0,0,0,0}, c1v[4] = {0,0,0,0};

    {   // zero h stages (h[-1] = 0)
        int4 z = {0,0,0,0};
        ((int4*)h0st)[tid] = z; ((int4*)h0st)[tid + 512] = z;
        ((int4*)h1st)[tid] = z; ((int4*)h1st)[tid + 512] = z;
    }
    __syncthreads();

    uint8_t* const h0base = h0g + (size_t)grp * 16384;
    uint8_t* const h1base = h1g + (size_t)grp * 16384;
    const size_t PSTRIDE = (size_t)32 * 16384;
    uint tgt = 0;

    for (int p = 0; p <= NS; ++p) {
        // ===== layer 0 MFMA (t = p) =====
        if (p < NS) {
            f32x4 acc[2][2];
            #pragma unroll
            for (int rr = 0; rr < 2; ++rr) { acc[rr][0] = (f32x4){0,0,0,0}; acc[rr][1] = (f32x4){0,0,0,0}; }
            #pragma unroll
            for (int rr = 0; rr < 2; ++rr) {
                int r16 = (rtp * 2 + rr) * 16;
                long a0 = 0;
                if (kgrp == 0) a0 = *(const long*)(x8 + (size_t)(rowbase + r16 + lrow) * (NS * NI) + p * 8);
                acc[rr][0] = __builtin_amdgcn_mfma_f32_16x16x32_fp8_fp8(a0, wI0[0], acc[rr][0], 0, 0, 0);
                acc[rr][1] = __builtin_amdgcn_mfma_f32_16x16x32_fp8_fp8(a0, wI0[1], acc[rr][1], 0, 0, 0);
                #pragma unroll
                for (int kb = 0; kb < 8; ++kb) {
                    long af = *(const long*)&h0st[HADDR(r16 + lrow, kb * 32 + kgrp * 8)];
                    acc[rr][0] = __builtin_amdgcn_mfma_f32_16x16x32_fp8_fp8(af, wH0[0][kb], acc[rr][0], 0, 0, 0);
                    acc[rr][1] = __builtin_amdgcn_mfma_f32_16x16x32_fp8_fp8(af, wH0[1][kb], acc[rr][1], 0, 0, 0);
                }
            }
            #pragma unroll
            for (int rr = 0; rr < 2; ++rr)
            #pragma unroll
            for (int cc = 0; cc < 2; ++cc) {
                int colb = (ctp * 2 + cc) * 16 + lrow;
                #pragma unroll
                for (int r = 0; r < 4; ++r) {
                    int row = (rtp * 2 + rr) * 16 + kgrp * 4 + r;
                    gbuf[GIDX(row, colb)] = acc[rr][cc][r];
                }
            }
        }
        __syncthreads();   // S1: gates0 staged

        // ===== nonlin0 -> publish h0[p] =====
        if (p < NS) {
            uint8_t* dst = h0base + (size_t)(p & 1) * PSTRIDE;
            #pragma unroll
            for (int r = 0; r < 4; ++r) {
                int row = rb + r;
                float iv = gbuf[GIDX(row, uu)]      * INV_SC + bs0[0];
                float fv = gbuf[GIDX(row, 32 + uu)] * INV_SC + bs0[1];
                float gv = gbuf[GIDX(row, 64 + uu)] * INV_SC + bs0[2];
                float ov = gbuf[GIDX(row, 96 + uu)] * INV_SC + bs0[3];
                float c = sigm(fv) * c0v[r] + sigm(iv) * tanh_f(gv);
                c0v[r] = c;
                float h = sigm(ov) * tanh_f(c);
                dst[(size_t)row * 256 + slc * 32 + uu] = f2fp8(h * A_SC);
            }
        }

        // ===== layer 1 MFMA (t = p-1): inputs h0[p-1] (h0st) and h1[p-2] (h1st) =====
        f32x4 acc1[2][2];
        if (p >= 1) {
            #pragma unroll
            for (int rr = 0; rr < 2; ++rr) { acc1[rr][0] = (f32x4){0,0,0,0}; acc1[rr][1] = (f32x4){0,0,0,0}; }
            #pragma unroll
            for (int rr = 0; rr < 2; ++rr) {
                int r16 = (rtp * 2 + rr) * 16;
                #pragma unroll
                for (int kb = 0; kb < 8; ++kb) {
                    long af0 = *(const long*)&h0st[HADDR(r16 + lrow, kb * 32 + kgrp * 8)];
                    acc1[rr][0] = __builtin_amdgcn_mfma_f32_16x16x32_fp8_fp8(af0, wI1[0][kb], acc1[rr][0], 0, 0, 0);
                    acc1[rr][1] = __builtin_amdgcn_mfma_f32_16x16x32_fp8_fp8(af0, wI1[1][kb], acc1[rr][1], 0, 0, 0);
                    long af1 = *(const long*)&h1st[HADDR(r16 + lrow, kb * 32 + kgrp * 8)];
                    acc1[rr][0] = __builtin_amdgcn_mfma_f32_16x16x32_fp8_fp8(af1, wH1[0][kb], acc1[rr][0], 0, 0, 0);
                    acc1[rr][1] = __builtin_amdgcn_mfma_f32_16x16x32_fp8_fp8(af1, wH1[1][kb], acc1[rr][1], 0, 0, 0);
                }
            }
        }
        __syncthreads();   // S2: nonlin0 gbuf reads done
        if (p >= 1) {
            #pragma unroll
            for (int rr = 0; rr < 2; ++rr)
            #pragma unroll
            for (int cc = 0; cc < 2; ++cc) {
                int colb = (ctp * 2 + cc) * 16 + lrow;
                #pragma unroll
                for (int r = 0; r < 4; ++r) {
                    int row = (rtp * 2 + rr) * 16 + kgrp * 4 + r;
                    gbuf[GIDX(row, colb)] = acc1[rr][cc][r];
                }
            }
        }
        __syncthreads();   // S3: gates1 staged
        if (p >= 1) {
            uint8_t* dst = h1base + (size_t)((p - 1) & 1) * PSTRIDE;
            #pragma unroll
            for (int r = 0; r < 4; ++r) {
                int row = rb + r;
                float iv = gbuf[GIDX(row, uu)]      * INV_SC + bs1[0];
                float fv = gbuf[GIDX(row, 32 + uu)] * INV_SC + bs1[1];
                float gv = gbuf[GIDX(row, 64 + uu)] * INV_SC + bs1[2];
                float ov = gbuf[GIDX(row, 96 + uu)] * INV_SC + bs1[3];
                float c = sigm(fv) * c1v[r] + sigm(iv) * tanh_f(gv);
                c1v[r] = c;
                float h = sigm(ov) * tanh_f(c);
                dst[(size_t)row * 256 + slc * 32 + uu] = f2fp8(h * A_SC);
            }
        }
        __syncthreads();   // S4: all publishes drained (vmcnt(0) per wave at barrier)

        // ===== cluster barrier (8 WGs of this batch-group) =====
        tgt += 8;
        if (tid == 0) {
            __threadfence();
            atomicAdd(&ctrs[grp * 64], 1u);
            uint v; int guard = 0;
            do {
                v = __hip_atomic_load(&ctrs[grp * 64], __ATOMIC_ACQUIRE, __HIP_MEMORY_SCOPE_AGENT);
                __builtin_amdgcn_s_sleep(1);
            } while (v < tgt && ++guard < (1 << 22));
            __threadfence();
        }
        __syncthreads();   // S5: barrier passed

        // ===== restage h0[p], h1[p-1] global -> LDS =====
        {
            int row = tid >> 3, seg = tid & 7;
            const uint4* q0p = (const uint4*)(h0base + (size_t)(p & 1) * PSTRIDE + (size_t)row * 256 + seg * 32);
            uint4 q0 = q0p[0], q1 = q0p[1];
            *(long*)&h0st[HADDR(row, seg * 32 + 0)]  = ((long)q0.y << 32) | (long)q0.x;
            *(long*)&h0st[HADDR(row, seg * 32 + 8)]  = ((long)q0.w << 32) | (long)q0.z;
            *(long*)&h0st[HADDR(row, seg * 32 + 16)] = ((long)q1.y << 32) | (long)q1.x;
            *(long*)&h0st[HADDR(row, seg * 32 + 24)] = ((long)q1.w << 32) | (long)q1.z;
            const uint4* q2p = (const uint4*)(h1base + (size_t)((p + 1) & 1) * PSTRIDE + (size_t)row * 256 + seg * 32);
            uint4 q2 = q2p[0], q3 = q2p[1];
            *(long*)&h1st[HADDR(row, seg * 32 + 0)]  = ((long)q2.y << 32) | (long)q2.x;
            *(long*)&h1st[HADDR(row, seg * 32 + 8)]  = ((long)q2.w << 32) | (long)q2.z;
            *(long*)&h1st[HADDR(row, seg * 32 + 16)] = ((long)q3.y << 32) | (long)q3.x;
            *(long*)&h1st[HADDR(row, seg * 32 + 24)] = ((long)q3.w << 32) | (long)q3.z;
        }
        __syncthreads();   // S6: stages ready for next phase
    }

    // ===== FC head: y = h1[127] @ Wfc^T + bfc (h1st holds h1[127]) =====
    if (slc < 4 && w < 4) {
        f32x4 af = (f32x4){0,0,0,0};
        #pragma unroll
        for (int kb = 0; kb < 8; ++kb) {
            long a  = *(const long*)&h1st[HADDR(w * 16 + lrow, kb * 32 + kgrp * 8)];
            long bf = *(const long*)(WfcP + (((size_t)slc * 8 + kb) * 64 + lane) * 8);
            af = __builtin_amdgcn_mfma_f32_16x16x32_fp8_fp8(a, bf, af, 0, 0, 0);
        }
        int col = slc * 16 + lrow;
        if (col < NK) {
            float bb = bfc[col];
            #pragma unroll
            for (int r = 0; r < 4; ++r) {
                int row = rowbase + w * 16 + kgrp * 4 + r;
                out[(size_t)row * NK + col] = af[r] * INV_SC + bb;
            }
        }
    }
}

// ---------------- IDM rollout (exact fp32) ----------------
__global__ void k_idm(const float* __restrict__ x, const float* __restrict__ s0,
                      const float* __restrict__ vl, float* __restrict__ out) {
    int b = blockIdx.x * 256 + threadIdx.x;
    if (b >= NB) return;
    float v = x[(size_t)b * NS * NI + (NS - 1) * NI + 0];
    float s = s0[b];
    float vlead = vl[b];
    const float den = 2.0f * sqrtf(A_MAX_ * B_SAFE_) + 1e-6f;
    float* o = out + (size_t)NB * NK + (size_t)b * NK;
    #pragma unroll 1
    for (int k = 0; k < NK; ++k) {
        float dv = vlead - v;
        float sc = fmaxf(s, 1e-6f);
        float ss = fmaxf(S0_ + v * T_HW_ + v * dv / den, 0.0f);
        float a = A_MAX_ * (1.0f - v / V_DES_ - (ss / sc) * (ss / sc));
        v = fmaxf(v + DT_ * a, 0.0f);
        s = fmaxf(s + dv * DT_, 1e-6f);
        o[k] = v;
    }
}

// ---------------- launch ----------------
extern "C" void kernel_launch(void* const* d_in, const int* in_sizes, int n_in,
                              void* d_out, int out_size, void* d_ws, size_t ws_size,
                              hipStream_t stream) {
    const float* x    = (const float*)d_in[0];
    const float* s0   = (const float*)d_in[1];
    const float* vl   = (const float*)d_in[2];
    const float* Wih0 = (const float*)d_in[3];
    const float* Whh0 = (const float*)d_in[4];
    const float* bih0 = (const float*)d_in[5];
    const float* bhh0 = (const float*)d_in[6];
    const float* Wih1 = (const float*)d_in[7];
    const float* Whh1 = (const float*)d_in[8];
    const float* bih1 = (const float*)d_in[9];
    const float* bhh1 = (const float*)d_in[10];
    const float* Wfc  = (const float*)d_in[11];
    const float* bfc  = (const float*)d_in[12];
    float* out = (float*)d_out;

    uint8_t* ws = (uint8_t*)d_ws;
    size_t off = 0;
    auto alloc = [&](size_t n) { uint8_t* p = ws + off; off += (n + 255) & ~(size_t)255; return p; };
    uint8_t* Wih0P = alloc(64 * 1 * 64 * 8);
    uint8_t* Whh0P = alloc(64 * 8 * 64 * 8);
    uint8_t* Wih1P = alloc(64 * 8 * 64 * 8);
    uint8_t* Whh1P = alloc(64 * 8 * 64 * 8);
    uint8_t* WfcP  = alloc(4 * 8 * 64 * 8);
    float* b0 = (float*)alloc(NG * 4);
    float* b1 = (float*)alloc(NG * 4);
    uint8_t* x8 = alloc((size_t)NB * NS * NI);
    // h exchange zone (memset each launch): h0g | h1g | ctrs, contiguous
    uint8_t* h0g = alloc(2u * 32 * 64 * 256);
    uint8_t* h1g = alloc(2u * 32 * 64 * 256);
    uint*    ctrs = (uint*)alloc(32 * 256);
    size_t hz = (size_t)(((uint8_t*)ctrs + 32 * 256) - h0g);

    k_pack<<<(64 * 1 * 64 + 255) / 256, 256, 0, stream>>>(Wih0, Wih0P, 64, 1, NG, NI);
    k_pack<<<(64 * 8 * 64 + 255) / 256, 256, 0, stream>>>(Whh0, Whh0P, 64, 8, NG, NH);
    k_pack<<<(64 * 8 * 64 + 255) / 256, 256, 0, stream>>>(Wih1, Wih1P, 64, 8, NG, NH);
    k_pack<<<(64 * 8 * 64 + 255) / 256, 256, 0, stream>>>(Whh1, Whh1P, 64, 8, NG, NH);
    k_pack<<<(4 * 8 * 64 + 255) / 256, 256, 0, stream>>>(Wfc, WfcP, 4, 8, NK, NH);
    k_bias<<<(2 * NG + 255) / 256, 256, 0, stream>>>(bih0, bhh0, bih1, bhh1, b0, b1);
    k_x8<<<(NB * NS * NI + 255) / 256, 256, 0, stream>>>(x, x8);
    hipMemsetAsync(h0g, 0, hz, stream);

    void* kargs[] = { (void*)&x8, (void*)&Wih0P, (void*)&Whh0P, (void*)&Wih1P, (void*)&Whh1P,
                      (void*)&WfcP, (void*)&b0, (void*)&b1, (void*)&bfc,
                      (void*)&h0g, (void*)&h1g, (void*)&ctrs, (void*)&out };
    hipError_t ce = hipLaunchCooperativeKernel((const void*)k_lstm2, dim3(256), dim3(512), kargs, 0, stream);
    if (ce != hipSuccess) {
        k_lstm2<<<256, 512, 0, stream>>>(x8, Wih0P, Whh0P, Wih1P, Whh1P, WfcP, b0, b1, bfc, h0g, h1g, ctrs, out);
    }
    k_idm<<<(NB + 255) / 256, 256, 0, stream>>>(x, s0, vl, out);
}

// Round 3
// 924.069 us; speedup vs baseline: 5.3990x; 2.8024x over previous
//
#include <hip/hip_runtime.h>
#include <stdint.h>

typedef float f32x4 __attribute__((ext_vector_type(4)));
typedef unsigned int uint;
typedef unsigned long long ull;

#define NB 2048
#define NS 128
#define NI 8
#define NH 256
#define NG 1024   // 4*H
#define NK 50

#define A_SC 16.0f
#define W_SC 32.0f
#define INV_SC (1.0f/(A_SC*W_SC))

// IDM constants
#define DT_    0.1f
#define V_DES_ 12.64798288f
#define T_HW_  0.50284384f
#define A_MAX_ 0.10033688f
#define B_SAFE_ 4.98937183f
#define S0_    0.13082412f

// h stage in LDS: [32 rows][256 bytes]; bank = 2*granule mod 32, so XOR the
// granule with row&15 -> each 16-lane phase group hits 16 distinct bank-pairs.
#define HADDR(row, boff) (((row) << 8) + (((((boff) >> 3) ^ ((row) & 15)) & 31) << 3) + ((boff) & 7))
// gate buffer: [32 rows][256 cols] f32, XOR column swizzle (CF writes & reads)
#define GIDX(row, col) (((row) << 8) + ((col) ^ (((row) & 12) << 2)))

__device__ __forceinline__ uint8_t f2fp8(float v) {
    int r = __builtin_amdgcn_cvt_pk_fp8_f32(v, v, 0, false);
    return (uint8_t)(r & 0xff);
}
__device__ __forceinline__ float sigm(float x) { return 1.0f / (1.0f + __expf(-x)); }
__device__ __forceinline__ float tanh_f(float x) {
    x = fminf(fmaxf(x, -15.0f), 15.0f);
    float e = __expf(2.0f * x);
    return (e - 1.0f) / (e + 1.0f);
}

// ---------------- pre-pass kernels ----------------
__global__ void k_pack(const float* __restrict__ W, uint8_t* __restrict__ out,
                       int tiles, int KB, int Nsrc, int Ksrc) {
    int gid = blockIdx.x * 256 + threadIdx.x;
    int total = tiles * KB * 64;
    if (gid >= total) return;
    int lane = gid & 63;
    int kb   = (gid >> 6) % KB;
    int tile = gid / (64 * KB);
    int n = tile * 16 + (lane & 15);
    int kbase = kb * 32 + (lane >> 4) * 8;
    uint64_t wbits = 0;
    #pragma unroll
    for (int j = 0; j < 8; ++j) {
        int k = kbase + j;
        float v = (n < Nsrc && k < Ksrc) ? W[(size_t)n * Ksrc + k] * W_SC : 0.0f;
        wbits |= ((uint64_t)f2fp8(v)) << (8 * j);
    }
    *(uint64_t*)(out + (size_t)gid * 8) = wbits;
}

__global__ void k_bias(const float* __restrict__ bih0, const float* __restrict__ bhh0,
                       const float* __restrict__ bih1, const float* __restrict__ bhh1,
                       float* __restrict__ b0, float* __restrict__ b1) {
    int i = blockIdx.x * 256 + threadIdx.x;
    if (i < NG) b0[i] = bih0[i] + bhh0[i];
    else if (i < 2 * NG) b1[i - NG] = bih1[i - NG] + bhh1[i - NG];
}

__global__ void k_x8(const float* __restrict__ x, uint8_t* __restrict__ x8) {
    int i = blockIdx.x * 256 + threadIdx.x;
    if (i < NB * NS * NI) x8[i] = f2fp8(x[i] * A_SC);
}

// ---------------- weight-stationary LSTM, MALL-coherent exchange ----------------
// 256 WGs = 64 batch-groups (32 rows) x 4 gate-slices (64 units, all 4 gates).
// Weights in VGPRs for the whole kernel. h exchanged via relaxed agent-scope
// atomics (sc1: performed at the MALL) -- NO cache-wide fences anywhere.
__global__ __launch_bounds__(512, 2)
void k_lstm3(const uint8_t* __restrict__ x8,
             const uint8_t* __restrict__ Wih0P, const uint8_t* __restrict__ Whh0P,
             const uint8_t* __restrict__ Wih1P, const uint8_t* __restrict__ Whh1P,
             const uint8_t* __restrict__ WfcP,
             const float* __restrict__ bias0, const float* __restrict__ bias1,
             const float* __restrict__ bfc,
             uint8_t* __restrict__ h0g, uint8_t* __restrict__ h1g,
             uint* __restrict__ ctrs, float* __restrict__ out) {
    __shared__ uint8_t h0st[8192];   // h0[prev], fp8, HADDR layout
    __shared__ uint8_t h1st[8192];   // h1[prev-1]
    __shared__ float gA[8192];       // layer0 gate staging (32x256), GIDX
    __shared__ float gB[8192];       // layer1 gate staging

    const int tid  = threadIdx.x;
    const int w    = tid >> 6, lane = tid & 63;
    const int lrow = lane & 15, kgrp = lane >> 4;
    const int blk  = blockIdx.x;
    const int grp  = blk >> 2, slc = blk & 3;
    const int rowbase = grp * 32;
    const int g = w & 3, ub = w >> 1 & 0; // placeholder (unused)
    const int ubk = w >> 2;              // unit-block 0/1

    // ---- persistent weight fragments (HBM read exactly once) ----
    // wave w: gate (w&3), local units [32*(w>>2), +32) => global tiles
    // T = gate*16 + slc*4 + (w>>2)*2 + cc
    long wI0[2], wH0[2][8], wI1[2][8], wH1[2][8];
    #pragma unroll
    for (int cc = 0; cc < 2; ++cc) {
        int T = g * 16 + slc * 4 + ubk * 2 + cc;
        wI0[cc] = *(const long*)(Wih0P + ((size_t)T * 64 + lane) * 8);
        #pragma unroll
        for (int kb = 0; kb < 8; ++kb) {
            wH0[cc][kb] = *(const long*)(Whh0P + (((size_t)T * 8 + kb) * 64 + lane) * 8);
            wI1[cc][kb] = *(const long*)(Wih1P + (((size_t)T * 8 + kb) * 64 + lane) * 8);
            wH1[cc][kb] = *(const long*)(Whh1P + (((size_t)T * 8 + kb) * 64 + lane) * 8);
        }
    }

    // nonlinearity ownership: thread -> local unit uu (of 64), rows rb..rb+3
    const int uu = tid & 63;
    const int rb = (tid >> 6) * 4;
    float bs0[4], bs1[4];
    #pragma unroll
    for (int q = 0; q < 4; ++q) {
        int n = q * 256 + slc * 64 + uu;
        bs0[q] = bias0[n]; bs1[q] = bias1[n];
    }
    float c0v[4] = {0,0,0,0}, c1v[4] = {0,0,0,0};

    { int4 z = {0,0,0,0}; ((int4*)h0st)[tid] = z; ((int4*)h1st)[tid] = z; }
    __syncthreads();

    uint8_t* const h0base = h0g + (size_t)grp * 16384;   // [par][32][256]
    uint8_t* const h1base = h1g + (size_t)grp * 16384;
    uint* const myctr = ctrs + grp * 16;
    uint tgt = 0;

    for (int p = 0; p <= NS; ++p) {
        // ===== layer 0 MFMA (t = p): g0 = x_t@Wih0^T + h0[p-1]@Whh0^T =====
        if (p < NS) {
            f32x4 acc[2][2];
            #pragma unroll
            for (int rr = 0; rr < 2; ++rr) { acc[rr][0] = (f32x4){0,0,0,0}; acc[rr][1] = (f32x4){0,0,0,0}; }
            #pragma unroll
            for (int rr = 0; rr < 2; ++rr) {
                long a0 = 0;
                if (kgrp == 0) a0 = *(const long*)(x8 + (size_t)(rowbase + rr * 16 + lrow) * (NS * NI) + p * 8);
                acc[rr][0] = __builtin_amdgcn_mfma_f32_16x16x32_fp8_fp8(a0, wI0[0], acc[rr][0], 0, 0, 0);
                acc[rr][1] = __builtin_amdgcn_mfma_f32_16x16x32_fp8_fp8(a0, wI0[1], acc[rr][1], 0, 0, 0);
                #pragma unroll
                for (int kb = 0; kb < 8; ++kb) {
                    long af = *(const long*)&h0st[HADDR(rr * 16 + lrow, kb * 32 + kgrp * 8)];
                    acc[rr][0] = __builtin_amdgcn_mfma_f32_16x16x32_fp8_fp8(af, wH0[0][kb], acc[rr][0], 0, 0, 0);
                    acc[rr][1] = __builtin_amdgcn_mfma_f32_16x16x32_fp8_fp8(af, wH0[1][kb], acc[rr][1], 0, 0, 0);
                }
            }
            #pragma unroll
            for (int rr = 0; rr < 2; ++rr)
            #pragma unroll
            for (int cc = 0; cc < 2; ++cc) {
                int colb = g * 64 + ubk * 32 + cc * 16 + lrow;
                #pragma unroll
                for (int r = 0; r < 4; ++r)
                    gA[GIDX(rr * 16 + kgrp * 4 + r, colb)] = acc[rr][cc][r];
            }
        }
        __syncthreads();   // S1: gates0 staged

        // ===== nonlin0 -> publish h0[p] (relaxed agent byte stores -> MALL) =====
        if (p < NS) {
            uint8_t* dst = h0base + (size_t)(p & 1) * 8192;
            #pragma unroll
            for (int r = 0; r < 4; ++r) {
                int row = rb + r;
                float iv = gA[GIDX(row, uu)]       * INV_SC + bs0[0];
                float fv = gA[GIDX(row, 64 + uu)]  * INV_SC + bs0[1];
                float gv = gA[GIDX(row, 128 + uu)] * INV_SC + bs0[2];
                float ov = gA[GIDX(row, 192 + uu)] * INV_SC + bs0[3];
                float c = sigm(fv) * c0v[r] + sigm(iv) * tanh_f(gv);
                c0v[r] = c;
                float h = sigm(ov) * tanh_f(c);
                __hip_atomic_store(dst + row * 256 + slc * 64 + uu, f2fp8(h * A_SC),
                                   __ATOMIC_RELAXED, __HIP_MEMORY_SCOPE_AGENT);
            }
        }

        // ===== layer 1 MFMA (t = p-1): h0[p-1]@Wih1^T + h1[p-2]@Whh1^T =====
        if (p >= 1) {
            f32x4 acc1[2][2];
            #pragma unroll
            for (int rr = 0; rr < 2; ++rr) { acc1[rr][0] = (f32x4){0,0,0,0}; acc1[rr][1] = (f32x4){0,0,0,0}; }
            #pragma unroll
            for (int rr = 0; rr < 2; ++rr) {
                #pragma unroll
                for (int kb = 0; kb < 8; ++kb) {
                    long af0 = *(const long*)&h0st[HADDR(rr * 16 + lrow, kb * 32 + kgrp * 8)];
                    acc1[rr][0] = __builtin_amdgcn_mfma_f32_16x16x32_fp8_fp8(af0, wI1[0][kb], acc1[rr][0], 0, 0, 0);
                    acc1[rr][1] = __builtin_amdgcn_mfma_f32_16x16x32_fp8_fp8(af0, wI1[1][kb], acc1[rr][1], 0, 0, 0);
                    long af1 = *(const long*)&h1st[HADDR(rr * 16 + lrow, kb * 32 + kgrp * 8)];
                    acc1[rr][0] = __builtin_amdgcn_mfma_f32_16x16x32_fp8_fp8(af1, wH1[0][kb], acc1[rr][0], 0, 0, 0);
                    acc1[rr][1] = __builtin_amdgcn_mfma_f32_16x16x32_fp8_fp8(af1, wH1[1][kb], acc1[rr][1], 0, 0, 0);
                }
            }
            #pragma unroll
            for (int rr = 0; rr < 2; ++rr)
            #pragma unroll
            for (int cc = 0; cc < 2; ++cc) {
                int colb = g * 64 + ubk * 32 + cc * 16 + lrow;
                #pragma unroll
                for (int r = 0; r < 4; ++r)
                    gB[GIDX(rr * 16 + kgrp * 4 + r, colb)] = acc1[rr][cc][r];
            }
        }
        __syncthreads();   // S2: gates1 staged, nonlin0 gA reads done

        if (p >= 1) {
            uint8_t* dst = h1base + (size_t)((p - 1) & 1) * 8192;
            #pragma unroll
            for (int r = 0; r < 4; ++r) {
                int row = rb + r;
                float iv = gB[GIDX(row, uu)]       * INV_SC + bs1[0];
                float fv = gB[GIDX(row, 64 + uu)]  * INV_SC + bs1[1];
                float gv = gB[GIDX(row, 128 + uu)] * INV_SC + bs1[2];
                float ov = gB[GIDX(row, 192 + uu)] * INV_SC + bs1[3];
                float c = sigm(fv) * c1v[r] + sigm(iv) * tanh_f(gv);
                c1v[r] = c;
                float h = sigm(ov) * tanh_f(c);
                __hip_atomic_store(dst + row * 256 + slc * 64 + uu, f2fp8(h * A_SC),
                                   __ATOMIC_RELAXED, __HIP_MEMORY_SCOPE_AGENT);
            }
        }
        __syncthreads();   // S3: all publish stores drained (vmcnt(0) at barrier)

        // ===== cluster barrier: 4 WGs, relaxed agent atomics (no cache ops) =====
        tgt += 4;
        if (tid == 0) {
            __hip_atomic_fetch_add(myctr, 1u, __ATOMIC_RELAXED, __HIP_MEMORY_SCOPE_AGENT);
            int gd = 0;
            while (__hip_atomic_load(myctr, __ATOMIC_RELAXED, __HIP_MEMORY_SCOPE_AGENT) < tgt) {
                __builtin_amdgcn_s_sleep(1);
                if (++gd >= (1 << 22)) break;
            }
        }
        __syncthreads();   // S4: barrier passed

        // ===== restage h0[p], h1[p-1]: MALL -> LDS =====
        {
            int rrow = tid & 31, seg = tid >> 5;   // 16 segs x 16B
            const ull* s0p = (const ull*)(h0base + (size_t)(p & 1) * 8192 + rrow * 256 + seg * 16);
            const ull* s1p = (const ull*)(h1base + (size_t)((p + 1) & 1) * 8192 + rrow * 256 + seg * 16);
            #pragma unroll
            for (int j = 0; j < 2; ++j) {
                ull q0 = __hip_atomic_load(s0p + j, __ATOMIC_RELAXED, __HIP_MEMORY_SCOPE_AGENT);
                ull q1 = __hip_atomic_load(s1p + j, __ATOMIC_RELAXED, __HIP_MEMORY_SCOPE_AGENT);
                *(ull*)&h0st[HADDR(rrow, seg * 16 + j * 8)] = q0;
                *(ull*)&h1st[HADDR(rrow, seg * 16 + j * 8)] = q1;
            }
        }
        __syncthreads();   // S5: stages ready for next phase
    }

    // ===== FC head: y = h1[127] @ Wfc^T + bfc (h1st holds h1[127]) =====
    if (w < 2) {
        f32x4 a = (f32x4){0,0,0,0};
        #pragma unroll
        for (int kb = 0; kb < 8; ++kb) {
            long af = *(const long*)&h1st[HADDR(w * 16 + lrow, kb * 32 + kgrp * 8)];
            long bf = *(const long*)(WfcP + (((size_t)slc * 8 + kb) * 64 + lane) * 8);
            a = __builtin_amdgcn_mfma_f32_16x16x32_fp8_fp8(af, bf, a, 0, 0, 0);
        }
        int col = slc * 16 + lrow;
        if (col < NK) {
            float bb = bfc[col];
            #pragma unroll
            for (int r = 0; r < 4; ++r) {
                int row = rowbase + w * 16 + kgrp * 4 + r;
                out[(size_t)row * NK + col] = a[r] * INV_SC + bb;
            }
        }
    }
}

// ---------------- IDM rollout (exact fp32) ----------------
__global__ void k_idm(const float* __restrict__ x, const float* __restrict__ s0,
                      const float* __restrict__ vl, float* __restrict__ out) {
    int b = blockIdx.x * 256 + threadIdx.x;
    if (b >= NB) return;
    float v = x[(size_t)b * NS * NI + (NS - 1) * NI + 0];
    float s = s0[b];
    float vlead = vl[b];
    const float den = 2.0f * sqrtf(A_MAX_ * B_SAFE_) + 1e-6f;
    float* o = out + (size_t)NB * NK + (size_t)b * NK;
    #pragma unroll 1
    for (int k = 0; k < NK; ++k) {
        float dv = vlead - v;
        float sc = fmaxf(s, 1e-6f);
        float ss = fmaxf(S0_ + v * T_HW_ + v * dv / den, 0.0f);
        float a = A_MAX_ * (1.0f - v / V_DES_ - (ss / sc) * (ss / sc));
        v = fmaxf(v + DT_ * a, 0.0f);
        s = fmaxf(s + dv * DT_, 1e-6f);
        o[k] = v;
    }
}

// ---------------- launch ----------------
extern "C" void kernel_launch(void* const* d_in, const int* in_sizes, int n_in,
                              void* d_out, int out_size, void* d_ws, size_t ws_size,
                              hipStream_t stream) {
    const float* x    = (const float*)d_in[0];
    const float* s0   = (const float*)d_in[1];
    const float* vl   = (const float*)d_in[2];
    const float* Wih0 = (const float*)d_in[3];
    const float* Whh0 = (const float*)d_in[4];
    const float* bih0 = (const float*)d_in[5];
    const float* bhh0 = (const float*)d_in[6];
    const float* Wih1 = (const float*)d_in[7];
    const float* Whh1 = (const float*)d_in[8];
    const float* bih1 = (const float*)d_in[9];
    const float* bhh1 = (const float*)d_in[10];
    const float* Wfc  = (const float*)d_in[11];
    const float* bfc  = (const float*)d_in[12];
    float* out = (float*)d_out;

    uint8_t* ws = (uint8_t*)d_ws;
    size_t off = 0;
    auto alloc = [&](size_t n) { uint8_t* p = ws + off; off += (n + 255) & ~(size_t)255; return p; };
    uint8_t* Wih0P = alloc(64 * 1 * 64 * 8);
    uint8_t* Whh0P = alloc(64 * 8 * 64 * 8);
    uint8_t* Wih1P = alloc(64 * 8 * 64 * 8);
    uint8_t* Whh1P = alloc(64 * 8 * 64 * 8);
    uint8_t* WfcP  = alloc(4 * 8 * 64 * 8);
    float* b0 = (float*)alloc(NG * 4);
    float* b1 = (float*)alloc(NG * 4);
    uint8_t* x8 = alloc((size_t)NB * NS * NI);
    // h exchange zone (memset each launch): h0g | h1g | ctrs, contiguous
    uint8_t* h0g = alloc((size_t)64 * 16384);
    uint8_t* h1g = alloc((size_t)64 * 16384);
    uint*    ctrs = (uint*)alloc(64 * 64);
    size_t hz = (size_t)(((uint8_t*)ctrs + 64 * 64) - h0g);

    k_pack<<<(64 * 1 * 64 + 255) / 256, 256, 0, stream>>>(Wih0, Wih0P, 64, 1, NG, NI);
    k_pack<<<(64 * 8 * 64 + 255) / 256, 256, 0, stream>>>(Whh0, Whh0P, 64, 8, NG, NH);
    k_pack<<<(64 * 8 * 64 + 255) / 256, 256, 0, stream>>>(Wih1, Wih1P, 64, 8, NG, NH);
    k_pack<<<(64 * 8 * 64 + 255) / 256, 256, 0, stream>>>(Whh1, Whh1P, 64, 8, NG, NH);
    k_pack<<<(4 * 8 * 64 + 255) / 256, 256, 0, stream>>>(Wfc, WfcP, 4, 8, NK, NH);
    k_bias<<<(2 * NG + 255) / 256, 256, 0, stream>>>(bih0, bhh0, bih1, bhh1, b0, b1);
    k_x8<<<(NB * NS * NI + 255) / 256, 256, 0, stream>>>(x, x8);
    hipMemsetAsync(h0g, 0, hz, stream);

    void* kargs[] = { (void*)&x8, (void*)&Wih0P, (void*)&Whh0P, (void*)&Wih1P, (void*)&Whh1P,
                      (void*)&WfcP, (void*)&b0, (void*)&b1, (void*)&bfc,
                      (void*)&h0g, (void*)&h1g, (void*)&ctrs, (void*)&out };
    hipError_t ce = hipLaunchCooperativeKernel((const void*)k_lstm3, dim3(256), dim3(512), kargs, 0, stream);
    if (ce != hipSuccess) {
        k_lstm3<<<256, 512, 0, stream>>>(x8, Wih0P, Whh0P, Wih1P, Whh1P, WfcP, b0, b1, bfc, h0g, h1g, ctrs, out);
    }
    k_idm<<<(NB + 255) / 256, 256, 0, stream>>>(x, s0, vl, out);
}